// Round 1
// baseline (109.739 us; speedup 1.0000x reference)
//
#include <hip/hip_runtime.h>

// BipolarMorphological2D SMorph:
//   out[b,o,s] = exp(sm(p1,k1)) - exp(sm(p1,k2)) - exp(sm(p2,k1)) + exp(sm(p2,k2)) + bias[o]
// with sm = sum(z*e^z)/sum(e^z), z = log(max(+/-x,0.1)) + kf[p,o].
// Factorization: e^z = m * e^kf ; z*e^z = (m*lm)*e^kf + m*(kf*e^kf)
// -> 12 fp32 GEMM-like reductions over P=288, no transcendentals in the hot loop.

#define BB   4
#define CC   32
#define HH   32
#define WW   32
#define OO   64
#define HO   30
#define WO   30
#define NSP  (HO*WO)   // 900 spatial positions per image
#define SREG 4         // spatial positions register-blocked per wave

// ---- prep: per-pixel A = (mp, mp*log mp, mn, mn*log mn) in [b,h,w,c] float4 layout
//            per-(p,o) Bm = (e^k1, k1*e^k1, e^k2, k2*e^k2) float4
__global__ __launch_bounds__(256) void smorph_prep(
    const float* __restrict__ x, const float* __restrict__ k1,
    const float* __restrict__ k2, float4* __restrict__ A, float4* __restrict__ Bm)
{
    int t = blockIdx.x * 256 + threadIdx.x;
    if (t < BB*CC*HH*WW) {
        float v = x[t];
        int b = t >> 15, c = (t >> 10) & 31, h = (t >> 5) & 31, w = t & 31;
        float mp = fmaxf(v, 0.1f), mn = fmaxf(-v, 0.1f);
        A[((b*HH + h)*WW + w)*CC + c] =
            make_float4(mp, mp*logf(mp), mn, mn*logf(mn));
    }
    if (t < 9*CC*OO) {
        float a = k1[t], bb = k2[t];
        float e1 = expf(a), e2 = expf(bb);
        Bm[t] = make_float4(e1, a*e1, e2, bb*e2);
    }
}

// ---- main: block = 4 waves x 64 lanes; lane = o; each wave does SREG spatial pos
__global__ __launch_bounds__(256) void smorph_main(
    const float4* __restrict__ A, const float4* __restrict__ Bm,
    const float* __restrict__ bias, float* __restrict__ out)
{
    const int o  = threadIdx.x & 63;
    const int wv = threadIdx.x >> 6;
    const int b  = blockIdx.y;
    const int sbase = blockIdx.x * (4*SREG) + wv * SREG;

    int ho[SREG], wo[SREG];
#pragma unroll
    for (int t = 0; t < SREG; ++t) {
        int s = sbase + t; if (s > NSP-1) s = NSP-1;   // clamp tail (stores masked)
        ho[t] = s / WO; wo[t] = s - ho[t]*WO;
    }

    float dp1[SREG] = {}, dp2[SREG] = {}, dn1[SREG] = {}, dn2[SREG] = {};
    float np1[SREG] = {}, np2[SREG] = {}, nn1[SREG] = {}, nn2[SREG] = {};

#pragma unroll
    for (int i = 0; i < 3; ++i) {
#pragma unroll
        for (int j = 0; j < 3; ++j) {
            const float4* Bp = Bm + (size_t)((i*3 + j)*CC)*OO + o;
            int abase[SREG];
#pragma unroll
            for (int t = 0; t < SREG; ++t)
                abase[t] = ((b*HH + ho[t] + i)*WW + (wo[t] + j))*CC;
#pragma unroll 8
            for (int c = 0; c < CC; ++c) {
                float4 Bv = Bp[(size_t)c*OO];          // coalesced across lanes (o)
                float4 Av[SREG];
#pragma unroll
                for (int t = 0; t < SREG; ++t) Av[t] = A[abase[t] + c];  // wave-uniform
#pragma unroll
                for (int t = 0; t < SREG; ++t) {
                    dp1[t] = fmaf(Av[t].x, Bv.x, dp1[t]);
                    np1[t] = fmaf(Av[t].y, Bv.x, np1[t]);
                    np1[t] = fmaf(Av[t].x, Bv.y, np1[t]);
                    dp2[t] = fmaf(Av[t].x, Bv.z, dp2[t]);
                    np2[t] = fmaf(Av[t].y, Bv.z, np2[t]);
                    np2[t] = fmaf(Av[t].x, Bv.w, np2[t]);
                    dn1[t] = fmaf(Av[t].z, Bv.x, dn1[t]);
                    nn1[t] = fmaf(Av[t].w, Bv.x, nn1[t]);
                    nn1[t] = fmaf(Av[t].z, Bv.y, nn1[t]);
                    dn2[t] = fmaf(Av[t].z, Bv.z, dn2[t]);
                    nn2[t] = fmaf(Av[t].w, Bv.z, nn2[t]);
                    nn2[t] = fmaf(Av[t].z, Bv.w, nn2[t]);
                }
            }
        }
    }

    const float bo = bias[o];
#pragma unroll
    for (int t = 0; t < SREG; ++t) {
        int s = sbase + t;
        if (s < NSP) {
            float r = expf(np1[t]/dp1[t]) - expf(np2[t]/dp2[t])
                    - expf(nn1[t]/dn1[t]) + expf(nn2[t]/dn2[t]) + bo;
            out[(size_t)(b*OO + o)*NSP + s] = r;
        }
    }
}

extern "C" void kernel_launch(void* const* d_in, const int* in_sizes, int n_in,
                              void* d_out, int out_size, void* d_ws, size_t ws_size,
                              hipStream_t stream) {
    const float* x    = (const float*)d_in[0];
    const float* k1   = (const float*)d_in[1];
    const float* k2   = (const float*)d_in[2];
    const float* bias = (const float*)d_in[3];

    float4* A  = (float4*)d_ws;                                   // 2 MB
    float4* Bm = (float4*)((char*)d_ws + (size_t)BB*HH*WW*CC*16); // 294 KB
    float*  out = (float*)d_out;

    hipLaunchKernelGGL(smorph_prep, dim3((BB*CC*HH*WW + 255)/256), dim3(256), 0, stream,
                       x, k1, k2, A, Bm);

    const int blocks_x = (NSP + 4*SREG - 1) / (4*SREG);   // 57
    hipLaunchKernelGGL(smorph_main, dim3(blocks_x, BB), dim3(256), 0, stream,
                       A, Bm, bias, out);
}

// Round 2
// 54.262 us; speedup vs baseline: 2.0224x; 2.0224x over previous
//
#include <hip/hip_runtime.h>

// BipolarMorphological2D SMorph:
//   out[b,o,s] = exp(sm(p1,k1)) - exp(sm(p1,k2)) - exp(sm(p2,k1)) + exp(sm(p2,k2)) + bias[o]
// with sm = sum(z*e^z)/sum(e^z), z = log(max(+/-x,0.1)) + kf[p,o].
// Factorization: e^z = m * e^kf ; z*e^z = (m*lm)*e^kf + m*(kf*e^kf)
// -> 12 fp32 FMA reductions over P=288, no transcendentals in the hot loop.
//
// R2 structure: 8 waves/block, 1 spatial position per wave (occupancy 0.89 ->
// 3.5 waves/SIMD), B-slice (32x64 float4 = 32KB) staged in LDS per (i,j) and
// shared by all 8 waves (L2 B-traffic 1GB -> 130MB, latency L2 -> LDS).

#define BB   4
#define CC   32
#define HH   32
#define WW   32
#define OO   64
#define HO   30
#define WO   30
#define NSP  (HO*WO)   // 900 spatial positions per image

// ---- prep: per-pixel A = (mp, mp*log mp, mn, mn*log mn) in [b,h,w,c] float4 layout
//            per-(p,o) Bm = (e^k1, k1*e^k1, e^k2, k2*e^k2) float4
__global__ __launch_bounds__(256) void smorph_prep(
    const float* __restrict__ x, const float* __restrict__ k1,
    const float* __restrict__ k2, float4* __restrict__ A, float4* __restrict__ Bm)
{
    int t = blockIdx.x * 256 + threadIdx.x;
    if (t < BB*CC*HH*WW) {
        float v = x[t];
        int b = t >> 15, c = (t >> 10) & 31, h = (t >> 5) & 31, w = t & 31;
        float mp = fmaxf(v, 0.1f), mn = fmaxf(-v, 0.1f);
        A[((b*HH + h)*WW + w)*CC + c] =
            make_float4(mp, mp*logf(mp), mn, mn*logf(mn));
    }
    if (t < 9*CC*OO) {
        float a = k1[t], bb = k2[t];
        float e1 = expf(a), e2 = expf(bb);
        Bm[t] = make_float4(e1, a*e1, e2, bb*e2);
    }
}

// ---- main: block = 8 waves x 64 lanes; lane = o; wave = one spatial position
__global__ __launch_bounds__(512) void smorph_main(
    const float4* __restrict__ A, const float4* __restrict__ Bm,
    const float* __restrict__ bias, float* __restrict__ out)
{
    __shared__ float4 Bs[CC*OO];   // 32 KB, layout [c][o]

    const int o  = threadIdx.x & 63;
    const int wv = threadIdx.x >> 6;           // 0..7
    const int b  = blockIdx.y;
    const int s  = blockIdx.x * 8 + wv;        // spatial position of this wave
    const int sc = (s < NSP) ? s : (NSP - 1);  // clamp tail, store masked
    const int ho = sc / WO, wo = sc - ho * WO;

    float dp1 = 0.f, np1 = 0.f, dp2 = 0.f, np2 = 0.f;
    float dn1 = 0.f, nn1 = 0.f, dn2 = 0.f, nn2 = 0.f;

    for (int ij = 0; ij < 9; ++ij) {
        __syncthreads();   // previous compute done before overwriting Bs
        {
            const float4* src = Bm + (size_t)ij * (CC*OO);
#pragma unroll
            for (int r = 0; r < (CC*OO)/512; ++r)
                Bs[threadIdx.x + 512*r] = src[threadIdx.x + 512*r];
        }
        __syncthreads();

        const int i = ij / 3, j = ij - 3*(ij/3);
        const float4* Ap = A + ((b*HH + ho + i)*WW + (wo + j))*CC;

#pragma unroll 8
        for (int c = 0; c < CC; ++c) {
            float4 Bv = Bs[c*OO + o];   // LDS, conflict-free (lanes 0-7 span 32 banks)
            float4 Av = Ap[c];          // wave-uniform 16B load
            dp1 = fmaf(Av.x, Bv.x, dp1);
            np1 = fmaf(Av.y, Bv.x, np1);
            np1 = fmaf(Av.x, Bv.y, np1);
            dp2 = fmaf(Av.x, Bv.z, dp2);
            np2 = fmaf(Av.y, Bv.z, np2);
            np2 = fmaf(Av.x, Bv.w, np2);
            dn1 = fmaf(Av.z, Bv.x, dn1);
            nn1 = fmaf(Av.w, Bv.x, nn1);
            nn1 = fmaf(Av.z, Bv.y, nn1);
            dn2 = fmaf(Av.z, Bv.z, dn2);
            nn2 = fmaf(Av.w, Bv.z, nn2);
            nn2 = fmaf(Av.z, Bv.w, nn2);
        }
    }

    if (s < NSP) {
        float r = expf(np1/dp1) - expf(np2/dp2)
                - expf(nn1/dn1) + expf(nn2/dn2) + bias[o];
        out[(size_t)(b*OO + o)*NSP + s] = r;
    }
}

extern "C" void kernel_launch(void* const* d_in, const int* in_sizes, int n_in,
                              void* d_out, int out_size, void* d_ws, size_t ws_size,
                              hipStream_t stream) {
    const float* x    = (const float*)d_in[0];
    const float* k1   = (const float*)d_in[1];
    const float* k2   = (const float*)d_in[2];
    const float* bias = (const float*)d_in[3];

    float4* A  = (float4*)d_ws;                                   // 2 MB
    float4* Bm = (float4*)((char*)d_ws + (size_t)BB*HH*WW*CC*16); // 294 KB
    float*  out = (float*)d_out;

    hipLaunchKernelGGL(smorph_prep, dim3((BB*CC*HH*WW + 255)/256), dim3(256), 0, stream,
                       x, k1, k2, A, Bm);

    const int blocks_x = (NSP + 7) / 8;   // 113
    hipLaunchKernelGGL(smorph_main, dim3(blocks_x, BB), dim3(512), 0, stream,
                       A, Bm, bias, out);
}

// Round 3
// 37.112 us; speedup vs baseline: 2.9570x; 1.4621x over previous
//
#include <hip/hip_runtime.h>

// BipolarMorphological2D SMorph:
//   out[b,o,s] = exp(sm(p1,k1)) - exp(sm(p1,k2)) - exp(sm(p2,k1)) + exp(sm(p2,k2)) + bias[o]
// with sm = sum(z*e^z)/sum(e^z), z = log(max(+/-x,0.1)) + kf[p,o].
// Factorization: e^z = m * e^kf ; z*e^z = (m*lm)*e^kf + m*(kf*e^kf)
// -> fp32 FMA reductions over P=288, no transcendentals in the hot loop.
//
// R3 structure: block = 16 waves (1024 thr). Wave w: sg=w&3 owns 4 spatial
// positions (SREG=4), kq=w>>2 owns c-range [8kq,8kq+8) (4-way K-split).
// One ds_read_b128 of B feeds 4 spatial x 6 pk_fma = 48 FMAs (LDS pipe 20->6us).
// A stored as (mp, mn, mp*lmp, mn*lmn) so pos/neg branches sit in lo/hi of
// v_pk_fma_f32 pairs; A addresses readfirstlane'd -> s_load (SMEM pipe).
// B double-buffered in LDS (1 barrier/phase); partials combined via LDS tree.

typedef float v2f __attribute__((ext_vector_type(2)));

#define BB   4
#define CC   32
#define HH   32
#define WW   32
#define OO   64
#define HO   30
#define WO   30
#define NSP  (HO*WO)   // 900

// ---- prep: A[b,h,w,c] = (mp, mn, mp*log mp, mn*log mn)
//            Bm[ij,c,o] = (e^k1, k1*e^k1, e^k2, k2*e^k2)
__global__ __launch_bounds__(256) void smorph_prep(
    const float* __restrict__ x, const float* __restrict__ k1,
    const float* __restrict__ k2, float4* __restrict__ A, float4* __restrict__ Bm)
{
    int t = blockIdx.x * 256 + threadIdx.x;
    if (t < BB*CC*HH*WW) {
        float v = x[t];
        int b = t >> 15, c = (t >> 10) & 31, h = (t >> 5) & 31, w = t & 31;
        float mp = fmaxf(v, 0.1f), mn = fmaxf(-v, 0.1f);
        A[((b*HH + h)*WW + w)*CC + c] =
            make_float4(mp, mn, mp*logf(mp), mn*logf(mn));
    }
    if (t < 9*CC*OO) {
        float a = k1[t], bb = k2[t];
        float e1 = expf(a), e2 = expf(bb);
        Bm[t] = make_float4(e1, a*e1, e2, bb*e2);
    }
}

__global__ __launch_bounds__(1024) void smorph_main(
    const float4* __restrict__ A, const float4* __restrict__ Bm,
    const float* __restrict__ bias, float* __restrict__ out)
{
    __shared__ float4 lds4[4096];          // 64 KB: 2 x 32KB B double-buffer
    v2f* ldsr = (v2f*)lds4;                // ... reused as 8 x 8KB combine slots

    const int tid = threadIdx.x;
    const int o   = tid & 63;
    const int w   = tid >> 6;              // wave 0..15
    const int sg  = w & 3;                 // spatial group
    const int kq  = w >> 2;                // c-quarter: [8kq, 8kq+8)
    const int b   = blockIdx.y;
    const int s0  = blockIdx.x * 16 + sg * 4;

    int abase[4];                          // float4 index of pixel (b,ho,wo), c=0
#pragma unroll
    for (int t = 0; t < 4; ++t) {
        int s = s0 + t; if (s > NSP-1) s = NSP-1;   // clamp tail, stores masked
        int ho = s / WO, wo = s - ho*WO;
        abase[t] = ((b*HH + ho)*WW + wo)*CC;
    }

    v2f P1d[4] = {}, P1n[4] = {}, P2d[4] = {}, P2n[4] = {};

    // prologue: stage ij=0 into buf 0
    lds4[tid]        = Bm[tid];
    lds4[tid + 1024] = Bm[tid + 1024];
    __syncthreads();

    int buf = 0;
    for (int ij = 0; ij < 9; ++ij) {
        if (ij < 8) {                      // prefetch next slice into other buffer
            const float4* src = Bm + (size_t)(ij+1)*2048;
            lds4[(buf^1)*2048 + tid]        = src[tid];
            lds4[(buf^1)*2048 + tid + 1024] = src[tid + 1024];
        }
        const int i = ij/3, j = ij - 3*(ij/3);

        const float4* Ap[4];               // wave-uniform -> s_load
#pragma unroll
        for (int t = 0; t < 4; ++t) {
            int u = __builtin_amdgcn_readfirstlane(abase[t] + (i*WW + j)*CC + kq*8);
            Ap[t] = A + u;
        }
        const float4* Bp = lds4 + buf*2048 + kq*8*OO + o;

#pragma unroll
        for (int c = 0; c < 8; ++c) {
            float4 Bv = Bp[c*OO];          // 1 ds_read_b128 feeds 24 pk_fma
            v2f be1 = {Bv.x, Bv.x}, bk1 = {Bv.y, Bv.y};
            v2f be2 = {Bv.z, Bv.z}, bk2 = {Bv.w, Bv.w};
#pragma unroll
            for (int t = 0; t < 4; ++t) {
                float4 Av = Ap[t][c];
                v2f a1 = {Av.x, Av.y};     // (mp, mn)
                v2f a2 = {Av.z, Av.w};     // (mp*lmp, mn*lmn)
                P1d[t] += a1 * be1;
                P1n[t] += a2 * be1;
                P1n[t] += a1 * bk1;
                P2d[t] += a1 * be2;
                P2n[t] += a2 * be2;
                P2n[t] += a1 * bk2;
            }
        }
        __syncthreads();                   // buf compute done + buf^1 staged
        buf ^= 1;
    }

    // ---- combine K-split partials: kq3->kq1? no: (kq2,kq3) -> (kq0,kq1), then kq1 -> kq0
    if (kq >= 2) {
        v2f* dst = ldsr + (w - 8)*1024 + o;
#pragma unroll
        for (int t = 0; t < 4; ++t) {
            dst[(t*4+0)*64] = P1d[t];
            dst[(t*4+1)*64] = P1n[t];
            dst[(t*4+2)*64] = P2d[t];
            dst[(t*4+3)*64] = P2n[t];
        }
    }
    __syncthreads();
    if (kq < 2) {
        const v2f* srcp = ldsr + w*1024 + o;
#pragma unroll
        for (int t = 0; t < 4; ++t) {
            P1d[t] += srcp[(t*4+0)*64];
            P1n[t] += srcp[(t*4+1)*64];
            P2d[t] += srcp[(t*4+2)*64];
            P2n[t] += srcp[(t*4+3)*64];
        }
    }
    __syncthreads();
    if (kq == 1) {
        v2f* dst = ldsr + (w - 4)*1024 + o;
#pragma unroll
        for (int t = 0; t < 4; ++t) {
            dst[(t*4+0)*64] = P1d[t];
            dst[(t*4+1)*64] = P1n[t];
            dst[(t*4+2)*64] = P2d[t];
            dst[(t*4+3)*64] = P2n[t];
        }
    }
    __syncthreads();
    if (kq == 0) {
        const v2f* srcp = ldsr + w*1024 + o;
        const float bo = bias[o];
#pragma unroll
        for (int t = 0; t < 4; ++t) {
            v2f d1 = P1d[t] + srcp[(t*4+0)*64];
            v2f n1 = P1n[t] + srcp[(t*4+1)*64];
            v2f d2 = P2d[t] + srcp[(t*4+2)*64];
            v2f n2 = P2n[t] + srcp[(t*4+3)*64];
            int s = s0 + t;
            if (s < NSP) {
                float r = expf(n1.x/d1.x) - expf(n2.x/d2.x)
                        - expf(n1.y/d1.y) + expf(n2.y/d2.y) + bo;
                out[(size_t)(b*OO + o)*NSP + s] = r;
            }
        }
    }
}

extern "C" void kernel_launch(void* const* d_in, const int* in_sizes, int n_in,
                              void* d_out, int out_size, void* d_ws, size_t ws_size,
                              hipStream_t stream) {
    const float* x    = (const float*)d_in[0];
    const float* k1   = (const float*)d_in[1];
    const float* k2   = (const float*)d_in[2];
    const float* bias = (const float*)d_in[3];

    float4* A  = (float4*)d_ws;                                   // 2 MB
    float4* Bm = (float4*)((char*)d_ws + (size_t)BB*HH*WW*CC*16); // 294 KB
    float*  out = (float*)d_out;

    hipLaunchKernelGGL(smorph_prep, dim3((BB*CC*HH*WW + 255)/256), dim3(256), 0, stream,
                       x, k1, k2, A, Bm);

    const int blocks_x = (NSP + 15) / 16;   // 57
    hipLaunchKernelGGL(smorph_main, dim3(blocks_x, BB), dim3(1024), 0, stream,
                       A, Bm, bias, out);
}

// Round 4
// 34.386 us; speedup vs baseline: 3.1913x; 1.0793x over previous
//
#include <hip/hip_runtime.h>

// BipolarMorphological2D SMorph:
//   out[b,o,s] = exp(sm(p1,k1)) - exp(sm(p1,k2)) - exp(sm(p2,k1)) + exp(sm(p2,k2)) + bias[o]
// with sm = sum(z*e^z)/sum(e^z), z = log(max(+/-x,0.1)) + kf[p,o].
// Factorization: e^z = m * e^kf ; z*e^z = (m*lm)*e^kf + m*(kf*e^kf)
// -> fp32 pk-FMA reductions over P=288, no transcendentals in the hot loop.
//
// R4 structure: block = 4 waves (256 thr), all owning the SAME 4 spatial
// positions, wave kq owns c-range [8kq,8kq+8). NO LDS / NO barriers in the
// main loop: B slices stream from L2 via coalesced global_load_dwordx4
// (vmcnt domain), A via wave-uniform scalar loads (sole lgkmcnt user ->
// fine-grained counting, no s_load/ds_read mixing). 900 blocks, 3600 waves,
// fully unrolled 9-phase loop -> compiler software-pipelines freely.
// K-split partials combined once at the end via 16KB LDS tree.

typedef float v2f __attribute__((ext_vector_type(2)));

#define BB   4
#define CC   32
#define HH   32
#define WW   32
#define OO   64
#define HO   30
#define WO   30
#define NSP  (HO*WO)   // 900 = 4*225, no tail

// ---- prep: A[b,h,w,c] = (mp, mn, mp*log mp, mn*log mn)
//            Bm[ij,c,o] = (e^k1, k1*e^k1, e^k2, k2*e^k2)
__global__ __launch_bounds__(256) void smorph_prep(
    const float* __restrict__ x, const float* __restrict__ k1,
    const float* __restrict__ k2, float4* __restrict__ A, float4* __restrict__ Bm)
{
    int t = blockIdx.x * 256 + threadIdx.x;
    if (t < BB*CC*HH*WW) {
        float v = x[t];
        int b = t >> 15, c = (t >> 10) & 31, h = (t >> 5) & 31, w = t & 31;
        float mp = fmaxf(v, 0.1f), mn = fmaxf(-v, 0.1f);
        A[((b*HH + h)*WW + w)*CC + c] =
            make_float4(mp, mn, mp*logf(mp), mn*logf(mn));
    }
    if (t < 9*CC*OO) {
        float a = k1[t], bb = k2[t];
        float e1 = expf(a), e2 = expf(bb);
        Bm[t] = make_float4(e1, a*e1, e2, bb*e2);
    }
}

__global__ __launch_bounds__(256, 4) void smorph_main(
    const float4* __restrict__ A, const float4* __restrict__ Bm,
    const float* __restrict__ bias, float* __restrict__ out)
{
    __shared__ v2f ldsr[2*16*64];   // 16 KB combine scratch (used only at end)

    const int tid = threadIdx.x;
    const int o   = tid & 63;
    const int kq  = __builtin_amdgcn_readfirstlane(tid >> 6);  // wave 0..3
    const int b   = blockIdx.y;
    const int s0  = blockIdx.x * 4;

    int abase[4];                   // float4 index of pixel (b,ho,wo), c=0 (uniform)
#pragma unroll
    for (int t = 0; t < 4; ++t) {
        int s = s0 + t;
        int ho = s / WO, wo = s - ho*WO;
        abase[t] = ((b*HH + ho)*WW + wo)*CC;
    }

    v2f P1d[4] = {}, P1n[4] = {}, P2d[4] = {}, P2n[4] = {};

    const float4* Bq = Bm + kq*8*OO + o;     // lane-coalesced B base

#pragma unroll
    for (int ij = 0; ij < 9; ++ij) {
        const int i = ij/3, j = ij - 3*(ij/3);

        float4 Bv[8];                        // 8x global_load_dwordx4, L2-hit
#pragma unroll
        for (int c = 0; c < 8; ++c) Bv[c] = Bq[(size_t)ij*(CC*OO) + c*OO];

#pragma unroll
        for (int t = 0; t < 4; ++t) {
            int off = __builtin_amdgcn_readfirstlane(abase[t] + (i*WW + j)*CC + kq*8);
            const float4* Ap = A + off;      // uniform -> s_load (128B/pixel)
#pragma unroll
            for (int c = 0; c < 8; ++c) {
                float4 Av = Ap[c];
                v2f a1 = {Av.x, Av.y};       // (mp, mn)
                v2f a2 = {Av.z, Av.w};       // (mp*lmp, mn*lmn)
                v2f be1 = {Bv[c].x, Bv[c].x}, bk1 = {Bv[c].y, Bv[c].y};
                v2f be2 = {Bv[c].z, Bv[c].z}, bk2 = {Bv[c].w, Bv[c].w};
                P1d[t] += a1 * be1;
                P1n[t] += a2 * be1;
                P1n[t] += a1 * bk1;
                P2d[t] += a1 * be2;
                P2n[t] += a2 * be2;
                P2n[t] += a1 * bk2;
            }
        }
    }

    // ---- combine K-split partials across the 4 waves
    if (kq >= 2) {
        v2f* dst = ldsr + (kq - 2)*1024 + o;
#pragma unroll
        for (int t = 0; t < 4; ++t) {
            dst[(t*4+0)*64] = P1d[t];
            dst[(t*4+1)*64] = P1n[t];
            dst[(t*4+2)*64] = P2d[t];
            dst[(t*4+3)*64] = P2n[t];
        }
    }
    __syncthreads();
    if (kq < 2) {
        const v2f* srcp = ldsr + kq*1024 + o;
#pragma unroll
        for (int t = 0; t < 4; ++t) {
            P1d[t] += srcp[(t*4+0)*64];
            P1n[t] += srcp[(t*4+1)*64];
            P2d[t] += srcp[(t*4+2)*64];
            P2n[t] += srcp[(t*4+3)*64];
        }
    }
    __syncthreads();
    if (kq == 1) {
        v2f* dst = ldsr + o;
#pragma unroll
        for (int t = 0; t < 4; ++t) {
            dst[(t*4+0)*64] = P1d[t];
            dst[(t*4+1)*64] = P1n[t];
            dst[(t*4+2)*64] = P2d[t];
            dst[(t*4+3)*64] = P2n[t];
        }
    }
    __syncthreads();
    if (kq == 0) {
        const v2f* srcp = ldsr + o;
        const float bo = bias[o];
#pragma unroll
        for (int t = 0; t < 4; ++t) {
            v2f d1 = P1d[t] + srcp[(t*4+0)*64];
            v2f n1 = P1n[t] + srcp[(t*4+1)*64];
            v2f d2 = P2d[t] + srcp[(t*4+2)*64];
            v2f n2 = P2n[t] + srcp[(t*4+3)*64];
            float r = expf(n1.x/d1.x) - expf(n2.x/d2.x)
                    - expf(n1.y/d1.y) + expf(n2.y/d2.y) + bo;
            out[(size_t)(b*OO + o)*NSP + (s0 + t)] = r;
        }
    }
}

extern "C" void kernel_launch(void* const* d_in, const int* in_sizes, int n_in,
                              void* d_out, int out_size, void* d_ws, size_t ws_size,
                              hipStream_t stream) {
    const float* x    = (const float*)d_in[0];
    const float* k1   = (const float*)d_in[1];
    const float* k2   = (const float*)d_in[2];
    const float* bias = (const float*)d_in[3];

    float4* A  = (float4*)d_ws;                                   // 2 MB
    float4* Bm = (float4*)((char*)d_ws + (size_t)BB*HH*WW*CC*16); // 294 KB
    float*  out = (float*)d_out;

    hipLaunchKernelGGL(smorph_prep, dim3((BB*CC*HH*WW + 255)/256), dim3(256), 0, stream,
                       x, k1, k2, A, Bm);

    hipLaunchKernelGGL(smorph_main, dim3(NSP/4, BB), dim3(256), 0, stream,
                       A, Bm, bias, out);
}

// Round 5
// 34.328 us; speedup vs baseline: 3.1968x; 1.0017x over previous
//
#include <hip/hip_runtime.h>

// BipolarMorphological2D SMorph:
//   out[b,o,s] = exp(sm(p1,k1)) - exp(sm(p1,k2)) - exp(sm(p2,k1)) + exp(sm(p2,k2)) + bias[o]
// with sm = sum(z*e^z)/sum(e^z), z = log(max(+/-x,0.1)) + kf[p,o].
// Factorization: e^z = m * e^kf ; z*e^z = (m*lm)*e^kf + m*(kf*e^kf)
// -> fp32 pk-FMA reductions over P=288, no transcendentals in the hot loop.
//
// R5: R4 grid (900x4 blocks, 4 waves: kq = c-quarter, SREG=4 spatial), but the
// main loop is an EXPLICIT register double-buffered pipeline on B at
// half-phase granularity (4x float4 = 16 VGPR per buffer): prefetch group n+1
// from L2 while 96 pk-FMAs compute group n (192 VALU cyc x 3.5 waves/SIMD
// covers ~250cyc L2 latency). Outer phase loop stays rolled (unroll 1) with
// incremental uniform A offsets -> ~80 VGPR, no scratch, 4 waves/SIMD budget.

typedef float v2f __attribute__((ext_vector_type(2)));

#define BB   4
#define CC   32
#define HH   32
#define WW   32
#define OO   64
#define HO   30
#define WO   30
#define NSP  (HO*WO)   // 900 = 4*225, no tail

// ---- prep: A[b,h,w,c] = (mp, mn, mp*log mp, mn*log mn)
//            Bm[ij,c,o] = (e^k1, k1*e^k1, e^k2, k2*e^k2)
__global__ __launch_bounds__(256) void smorph_prep(
    const float* __restrict__ x, const float* __restrict__ k1,
    const float* __restrict__ k2, float4* __restrict__ A, float4* __restrict__ Bm)
{
    int t = blockIdx.x * 256 + threadIdx.x;
    if (t < BB*CC*HH*WW) {
        float v = x[t];
        int b = t >> 15, c = (t >> 10) & 31, h = (t >> 5) & 31, w = t & 31;
        float mp = fmaxf(v, 0.1f), mn = fmaxf(-v, 0.1f);
        A[((b*HH + h)*WW + w)*CC + c] =
            make_float4(mp, mn, mp*logf(mp), mn*logf(mn));
    }
    if (t < 9*CC*OO) {
        float a = k1[t], bb = k2[t];
        float e1 = expf(a), e2 = expf(bb);
        Bm[t] = make_float4(e1, a*e1, e2, bb*e2);
    }
}

__global__ __launch_bounds__(256, 4) void smorph_main(
    const float4* __restrict__ A, const float4* __restrict__ Bm,
    const float* __restrict__ bias, float* __restrict__ out)
{
    __shared__ v2f ldsr[2*16*64];   // 16 KB combine scratch (used only at end)

    const int tid = threadIdx.x;
    const int o   = tid & 63;
    const int kq  = __builtin_amdgcn_readfirstlane(tid >> 6);  // wave 0..3
    const int b   = blockIdx.y;
    const int s0  = blockIdx.x * 4;

    int abase[4];                   // float4 index of pixel (b,ho,wo), c = kq*8
#pragma unroll
    for (int t = 0; t < 4; ++t) {
        int s = s0 + t;
        int ho = s / WO, wo = s - ho*WO;
        abase[t] = __builtin_amdgcn_readfirstlane(((b*HH + ho)*WW + wo)*CC + kq*8);
    }

    v2f P1d[4] = {}, P1n[4] = {}, P2d[4] = {}, P2n[4] = {};

    const float4* Bq = Bm + kq*8*OO + o;     // lane-coalesced B base

    float4 Bb0[4], Bb1[4];
    // prologue: prefetch phase 0, half 0
#pragma unroll
    for (int c = 0; c < 4; ++c) Bb0[c] = Bq[c*OO];

    int aoff = 0;   // (i*WW + j)*CC, uniform, updated incrementally
    int jj   = 0;   // j within row of the 3x3 window

#pragma unroll 1
    for (int ij = 0; ij < 9; ++ij) {
        const size_t bp = (size_t)ij * (CC*OO);
        const size_t bn = (size_t)(ij < 8 ? ij + 1 : 8) * (CC*OO);

        // issue half1 loads (overlaps half0 compute below)
#pragma unroll
        for (int c = 0; c < 4; ++c) Bb1[c] = Bq[bp + (4 + c)*OO];

        const float4* Ap0 = A + (abase[0] + aoff);
        const float4* Ap1 = A + (abase[1] + aoff);
        const float4* Ap2 = A + (abase[2] + aoff);
        const float4* Ap3 = A + (abase[3] + aoff);

        // ---- compute half0 (c = 0..3)
#pragma unroll
        for (int c = 0; c < 4; ++c) {
            v2f be1 = {Bb0[c].x, Bb0[c].x}, bk1 = {Bb0[c].y, Bb0[c].y};
            v2f be2 = {Bb0[c].z, Bb0[c].z}, bk2 = {Bb0[c].w, Bb0[c].w};
            const float4 Av[4] = {Ap0[c], Ap1[c], Ap2[c], Ap3[c]};
#pragma unroll
            for (int t = 0; t < 4; ++t) {
                v2f a1 = {Av[t].x, Av[t].y};
                v2f a2 = {Av[t].z, Av[t].w};
                P1d[t] += a1 * be1;
                P1n[t] += a2 * be1;
                P1n[t] += a1 * bk1;
                P2d[t] += a1 * be2;
                P2n[t] += a2 * be2;
                P2n[t] += a1 * bk2;
            }
        }

        // issue next phase half0 loads (overlaps half1 compute below)
#pragma unroll
        for (int c = 0; c < 4; ++c) Bb0[c] = Bq[bn + c*OO];

        // ---- compute half1 (c = 4..7)
#pragma unroll
        for (int c = 0; c < 4; ++c) {
            v2f be1 = {Bb1[c].x, Bb1[c].x}, bk1 = {Bb1[c].y, Bb1[c].y};
            v2f be2 = {Bb1[c].z, Bb1[c].z}, bk2 = {Bb1[c].w, Bb1[c].w};
            const float4 Av[4] = {Ap0[4+c], Ap1[4+c], Ap2[4+c], Ap3[4+c]};
#pragma unroll
            for (int t = 0; t < 4; ++t) {
                v2f a1 = {Av[t].x, Av[t].y};
                v2f a2 = {Av[t].z, Av[t].w};
                P1d[t] += a1 * be1;
                P1n[t] += a2 * be1;
                P1n[t] += a1 * bk1;
                P2d[t] += a1 * be2;
                P2n[t] += a2 * be2;
                P2n[t] += a1 * bk2;
            }
        }

        // advance A offset: +CC within a row, +(WW-2)*CC on row wrap
        aoff += (jj == 2) ? (WW - 2)*CC : CC;
        jj = (jj == 2) ? 0 : jj + 1;
    }

    // ---- combine K-split partials across the 4 waves
    if (kq >= 2) {
        v2f* dst = ldsr + (kq - 2)*1024 + o;
#pragma unroll
        for (int t = 0; t < 4; ++t) {
            dst[(t*4+0)*64] = P1d[t];
            dst[(t*4+1)*64] = P1n[t];
            dst[(t*4+2)*64] = P2d[t];
            dst[(t*4+3)*64] = P2n[t];
        }
    }
    __syncthreads();
    if (kq < 2) {
        const v2f* srcp = ldsr + kq*1024 + o;
#pragma unroll
        for (int t = 0; t < 4; ++t) {
            P1d[t] += srcp[(t*4+0)*64];
            P1n[t] += srcp[(t*4+1)*64];
            P2d[t] += srcp[(t*4+2)*64];
            P2n[t] += srcp[(t*4+3)*64];
        }
    }
    __syncthreads();
    if (kq == 1) {
        v2f* dst = ldsr + o;
#pragma unroll
        for (int t = 0; t < 4; ++t) {
            dst[(t*4+0)*64] = P1d[t];
            dst[(t*4+1)*64] = P1n[t];
            dst[(t*4+2)*64] = P2d[t];
            dst[(t*4+3)*64] = P2n[t];
        }
    }
    __syncthreads();
    if (kq == 0) {
        const v2f* srcp = ldsr + o;
        const float bo = bias[o];
#pragma unroll
        for (int t = 0; t < 4; ++t) {
            v2f d1 = P1d[t] + srcp[(t*4+0)*64];
            v2f n1 = P1n[t] + srcp[(t*4+1)*64];
            v2f d2 = P2d[t] + srcp[(t*4+2)*64];
            v2f n2 = P2n[t] + srcp[(t*4+3)*64];
            float r = expf(n1.x/d1.x) - expf(n2.x/d2.x)
                    - expf(n1.y/d1.y) + expf(n2.y/d2.y) + bo;
            out[(size_t)(b*OO + o)*NSP + (s0 + t)] = r;
        }
    }
}

extern "C" void kernel_launch(void* const* d_in, const int* in_sizes, int n_in,
                              void* d_out, int out_size, void* d_ws, size_t ws_size,
                              hipStream_t stream) {
    const float* x    = (const float*)d_in[0];
    const float* k1   = (const float*)d_in[1];
    const float* k2   = (const float*)d_in[2];
    const float* bias = (const float*)d_in[3];

    float4* A  = (float4*)d_ws;                                   // 2 MB
    float4* Bm = (float4*)((char*)d_ws + (size_t)BB*HH*WW*CC*16); // 294 KB
    float*  out = (float*)d_out;

    hipLaunchKernelGGL(smorph_prep, dim3((BB*CC*HH*WW + 255)/256), dim3(256), 0, stream,
                       x, k1, k2, A, Bm);

    hipLaunchKernelGGL(smorph_main, dim3(NSP/4, BB), dim3(256), 0, stream,
                       A, Bm, bias, out);
}